// Round 1
// baseline (503.451 us; speedup 1.0000x reference)
//
#include <hip/hip_runtime.h>
#include <math.h>

#define S_LEN 2048
#define DM    1024
#define NH    16
#define DH    64
#define CHUNK 64
#define NCH   (S_LEN / CHUNK)          // 32
#define ST_STRIDE (DH * DH + DH)       // 4160 floats per (head,chunk) state

__device__ __forceinline__ float softplus_f(float x) {
    return (x > 20.0f) ? x : log1pf(expf(x));
}

// Y = act(X @ W^T + b).  X: [2048][1024] row-major, W: [1024][1024] row-major (row = output feature).
// MODE 0: plain, Y[m*DM + n]                       (final O projection -> d_out)
// MODE 1: softplus((val)/scale[h]), head layout Y[(h*S+m)*DH + d]   (q, k)
// MODE 2: head layout, no softplus                                   (v)
template<int MODE>
__global__ __launch_bounds__(256)
void gemm_kernel(const float* __restrict__ X, const float* __restrict__ W,
                 const float* __restrict__ bias, const float* __restrict__ beta,
                 float* __restrict__ Y)
{
    __shared__ float Xs[16][132];   // [kk][row], padded: 132*4B = 528B = 16B-aligned rows
    __shared__ float Ws[16][68];    // [kk][col], 272B rows, 16B-aligned

    const int t  = threadIdx.x;
    const int tx = t & 15;          // col group (4 cols each)
    const int ty = t >> 4;          // row group (8 rows each)
    const int m0 = blockIdx.y * 128;
    const int n0 = blockIdx.x * 64;

    float acc[8][4];
#pragma unroll
    for (int i = 0; i < 8; ++i)
#pragma unroll
        for (int j = 0; j < 4; ++j) acc[i][j] = 0.0f;

    for (int kt = 0; kt < DM; kt += 16) {
        // stage X tile (128 rows x 16 k), transposed into Xs[kk][row]
#pragma unroll
        for (int u = 0; u < 2; ++u) {
            int f   = u * 256 + t;           // 512 float4 total
            int row = f >> 2, vec = f & 3;
            const float4 xv = *(const float4*)(X + (size_t)(m0 + row) * DM + kt + vec * 4);
            Xs[vec * 4 + 0][row] = xv.x;
            Xs[vec * 4 + 1][row] = xv.y;
            Xs[vec * 4 + 2][row] = xv.z;
            Xs[vec * 4 + 3][row] = xv.w;
        }
        {
            int row = t >> 2, vec = t & 3;   // 256 float4 total
            const float4 wv = *(const float4*)(W + (size_t)(n0 + row) * DM + kt + vec * 4);
            Ws[vec * 4 + 0][row] = wv.x;
            Ws[vec * 4 + 1][row] = wv.y;
            Ws[vec * 4 + 2][row] = wv.z;
            Ws[vec * 4 + 3][row] = wv.w;
        }
        __syncthreads();
#pragma unroll
        for (int kk = 0; kk < 16; ++kk) {
            const float4 a0 = *(const float4*)&Xs[kk][ty * 8];
            const float4 a1 = *(const float4*)&Xs[kk][ty * 8 + 4];
            const float4 b  = *(const float4*)&Ws[kk][tx * 4];
            const float av[8] = {a0.x, a0.y, a0.z, a0.w, a1.x, a1.y, a1.z, a1.w};
            const float bv[4] = {b.x, b.y, b.z, b.w};
#pragma unroll
            for (int i = 0; i < 8; ++i)
#pragma unroll
                for (int j = 0; j < 4; ++j) acc[i][j] += av[i] * bv[j];
        }
        __syncthreads();
    }

    if (MODE == 0) {
#pragma unroll
        for (int i = 0; i < 8; ++i) {
            const int m = m0 + ty * 8 + i;
            float4 o;
            o.x = acc[i][0] + bias[n0 + tx * 4 + 0];
            o.y = acc[i][1] + bias[n0 + tx * 4 + 1];
            o.z = acc[i][2] + bias[n0 + tx * 4 + 2];
            o.w = acc[i][3] + bias[n0 + tx * 4 + 3];
            *(float4*)(Y + (size_t)m * DM + n0 + tx * 4) = o;
        }
    } else {
        const int   nb  = n0 + tx * 4;      // 4 cols stay inside one head (nb multiple of 4, head = 64)
        const int   h   = nb >> 6;
        const int   d   = nb & 63;
        const float scl = (MODE == 1) ? (8.0f * expf(beta[h])) : 1.0f;
        const float inv = 1.0f / scl;
#pragma unroll
        for (int i = 0; i < 8; ++i) {
            const int m = m0 + ty * 8 + i;
            float v0 = acc[i][0] + bias[nb + 0];
            float v1 = acc[i][1] + bias[nb + 1];
            float v2 = acc[i][2] + bias[nb + 2];
            float v3 = acc[i][3] + bias[nb + 3];
            if (MODE == 1) {
                v0 = softplus_f(v0 * inv);
                v1 = softplus_f(v1 * inv);
                v2 = softplus_f(v2 * inv);
                v3 = softplus_f(v3 * inv);
            }
            float4 o; o.x = v0; o.y = v1; o.z = v2; o.w = v3;
            *(float4*)(Y + ((size_t)h * S_LEN + m) * DH + d) = o;
        }
    }
}

// Pass B: per (head, chunk) state  M[d][e] = sum_s K[s][d]*V[s][e],  ksum[d] = sum_s K[s][d]
__global__ __launch_bounds__(256)
void chunk_state_kernel(const float* __restrict__ k_ws, const float* __restrict__ v_ws,
                        float* __restrict__ st)
{
    __shared__ float Ks[64][64];    // [s][d]
    __shared__ float Vs[64][64];    // [s][e]
    const int c = blockIdx.x, h = blockIdx.y;
    const int t = threadIdx.x;
    const float* Kg = k_ws + ((size_t)h * S_LEN + c * CHUNK) * DH;
    const float* Vg = v_ws + ((size_t)h * S_LEN + c * CHUNK) * DH;
#pragma unroll
    for (int u = 0; u < 4; ++u) {
        int f = u * 256 + t;                 // 1024 float4 each
        ((float4*)&Ks[0][0])[f] = ((const float4*)Kg)[f];
        ((float4*)&Vs[0][0])[f] = ((const float4*)Vg)[f];
    }
    __syncthreads();

    const int tx = t & 15, ty = t >> 4;
    float acc[4][4];
#pragma unroll
    for (int i = 0; i < 4; ++i)
#pragma unroll
        for (int j = 0; j < 4; ++j) acc[i][j] = 0.0f;

    for (int s = 0; s < 64; ++s) {
        const float4 kd = *(const float4*)&Ks[s][ty * 4];
        const float4 ve = *(const float4*)&Vs[s][tx * 4];
        const float kv[4] = {kd.x, kd.y, kd.z, kd.w};
        const float vv[4] = {ve.x, ve.y, ve.z, ve.w};
#pragma unroll
        for (int i = 0; i < 4; ++i)
#pragma unroll
            for (int j = 0; j < 4; ++j) acc[i][j] += kv[i] * vv[j];
    }
    float* base = st + (size_t)(h * NCH + c) * ST_STRIDE;
#pragma unroll
    for (int i = 0; i < 4; ++i) {
        float4 o; o.x = acc[i][0]; o.y = acc[i][1]; o.z = acc[i][2]; o.w = acc[i][3];
        *(float4*)(base + (ty * 4 + i) * 64 + tx * 4) = o;
    }
    if (t < 64) {
        float s = 0.0f;
        for (int j = 0; j < 64; ++j) s += Ks[j][t];
        base[DH * DH + t] = s;
    }
}

// Pass D: per (head, chunk) output:
//   A = Q K^T (causal-masked, inclusive diagonal)
//   num = A V + Q @ KVprefix ;  den = rowsum(A) + Q . k1prefix ;  out = num/den
__global__ __launch_bounds__(256)
void attn_out_kernel(const float* __restrict__ q_ws, const float* __restrict__ k_ws,
                     const float* __restrict__ v_ws, const float* __restrict__ st,
                     float* __restrict__ out_pre)
{
    __shared__ float QsT[64][68];   // [d][i]  (transposed, padded for alignment + banks)
    __shared__ float KsT[64][68];   // [d][j]
    __shared__ float Vs[64][64];    // [j][e]
    __shared__ float As[64][65];    // [i][j]  masked scores
    __shared__ float KVp[64][64];   // [d][e]  prefix state
    __shared__ float k1p[64];

    const int c = blockIdx.x, h = blockIdx.y;
    const int t = threadIdx.x, tx = t & 15, ty = t >> 4;
    const size_t cbase = ((size_t)h * S_LEN + c * CHUNK) * DH;

    // stage Q,K transposed: lane-varying row -> conflict-free LDS scatter (global is L2-resident)
#pragma unroll
    for (int u = 0; u < 4; ++u) {
        int f = u * 256 + t;                 // f in [0,1024)
        int cg = f >> 6, row = f & 63;
        const int col4 = cg * 4;
        const float4 qv = *(const float4*)(q_ws + cbase + (size_t)row * DH + col4);
        QsT[col4 + 0][row] = qv.x;
        QsT[col4 + 1][row] = qv.y;
        QsT[col4 + 2][row] = qv.z;
        QsT[col4 + 3][row] = qv.w;
        const float4 kv = *(const float4*)(k_ws + cbase + (size_t)row * DH + col4);
        KsT[col4 + 0][row] = kv.x;
        KsT[col4 + 1][row] = kv.y;
        KsT[col4 + 2][row] = kv.z;
        KsT[col4 + 3][row] = kv.w;
    }
#pragma unroll
    for (int u = 0; u < 4; ++u) {
        int f = u * 256 + t;
        ((float4*)&Vs[0][0])[f] = ((const float4*)(v_ws + cbase))[f];
    }

    // prefix state accumulation (registers), then to LDS
    float kvp[4][4];
#pragma unroll
    for (int i = 0; i < 4; ++i)
#pragma unroll
        for (int j = 0; j < 4; ++j) kvp[i][j] = 0.0f;
    float k1r = 0.0f;
    for (int cp = 0; cp < c; ++cp) {
        const float* sb = st + (size_t)(h * NCH + cp) * ST_STRIDE;
#pragma unroll
        for (int i = 0; i < 4; ++i) {
            const float4 m4 = *(const float4*)(sb + (ty * 4 + i) * 64 + tx * 4);
            kvp[i][0] += m4.x; kvp[i][1] += m4.y; kvp[i][2] += m4.z; kvp[i][3] += m4.w;
        }
        if (t < 64) k1r += sb[DH * DH + t];
    }
#pragma unroll
    for (int i = 0; i < 4; ++i) {
        float4 o; o.x = kvp[i][0]; o.y = kvp[i][1]; o.z = kvp[i][2]; o.w = kvp[i][3];
        *(float4*)&KVp[ty * 4 + i][tx * 4] = o;
    }
    if (t < 64) k1p[t] = k1r;
    __syncthreads();

    // A = Q K^T  (tile i = ty*4.., j = tx*4..)
    float a[4][4];
#pragma unroll
    for (int i = 0; i < 4; ++i)
#pragma unroll
        for (int j = 0; j < 4; ++j) a[i][j] = 0.0f;
    for (int d = 0; d < 64; ++d) {
        const float4 qd = *(const float4*)&QsT[d][ty * 4];
        const float4 kd = *(const float4*)&KsT[d][tx * 4];
        const float qv[4] = {qd.x, qd.y, qd.z, qd.w};
        const float kv[4] = {kd.x, kd.y, kd.z, kd.w};
#pragma unroll
        for (int i = 0; i < 4; ++i)
#pragma unroll
            for (int j = 0; j < 4; ++j) a[i][j] += qv[i] * kv[j];
    }
#pragma unroll
    for (int i = 0; i < 4; ++i)
#pragma unroll
        for (int j = 0; j < 4; ++j) {
            const int gi = ty * 4 + i, gj = tx * 4 + j;
            As[gi][gj] = (gj <= gi) ? a[i][j] : 0.0f;
        }

    // inter-chunk: num += Q @ KVp ; den_inter = Q . k1p   (no sync needed yet: reads QsT/KVp/k1p only)
    float num[4][4];
#pragma unroll
    for (int i = 0; i < 4; ++i)
#pragma unroll
        for (int j = 0; j < 4; ++j) num[i][j] = 0.0f;
    for (int d = 0; d < 64; ++d) {
        const float4 qd = *(const float4*)&QsT[d][ty * 4];
        const float4 pe = *(const float4*)&KVp[d][tx * 4];
        const float qv[4] = {qd.x, qd.y, qd.z, qd.w};
        const float pv[4] = {pe.x, pe.y, pe.z, pe.w};
#pragma unroll
        for (int i = 0; i < 4; ++i)
#pragma unroll
            for (int j = 0; j < 4; ++j) num[i][j] += qv[i] * pv[j];
    }
    float den[4] = {0.0f, 0.0f, 0.0f, 0.0f};
    for (int d = 0; d < 64; ++d) {
        const float kp = k1p[d];
#pragma unroll
        for (int i = 0; i < 4; ++i) den[i] += QsT[d][ty * 4 + i] * kp;
    }
    __syncthreads();   // As fully written

    // intra-chunk: num += A V ; rowsum(A)
    float rs[4] = {0.0f, 0.0f, 0.0f, 0.0f};
    for (int j = 0; j < 64; ++j) {
        const float4 ve = *(const float4*)&Vs[j][tx * 4];
        const float vv[4] = {ve.x, ve.y, ve.z, ve.w};
#pragma unroll
        for (int i = 0; i < 4; ++i) {
            const float aij = As[ty * 4 + i][j];
            rs[i] += aij;
            num[i][0] += aij * vv[0];
            num[i][1] += aij * vv[1];
            num[i][2] += aij * vv[2];
            num[i][3] += aij * vv[3];
        }
    }

#pragma unroll
    for (int i = 0; i < 4; ++i) {
        const float dn = den[i] + rs[i];
        const float r  = 1.0f / dn;
        const int srow = c * CHUNK + ty * 4 + i;
        float4 o;
        o.x = num[i][0] * r; o.y = num[i][1] * r; o.z = num[i][2] * r; o.w = num[i][3] * r;
        *(float4*)(out_pre + (size_t)srow * DM + h * DH + tx * 4) = o;
    }
}

extern "C" void kernel_launch(void* const* d_in, const int* in_sizes, int n_in,
                              void* d_out, int out_size, void* d_ws, size_t ws_size,
                              hipStream_t stream)
{
    const float* x    = (const float*)d_in[0];
    const float* Wq   = (const float*)d_in[1];
    const float* bq   = (const float*)d_in[2];
    const float* Wk   = (const float*)d_in[3];
    const float* bk   = (const float*)d_in[4];
    const float* Wv   = (const float*)d_in[5];
    const float* bv   = (const float*)d_in[6];
    const float* Wo   = (const float*)d_in[7];
    const float* bo   = (const float*)d_in[8];
    const float* beta = (const float*)d_in[9];
    float* out = (float*)d_out;

    float* q_ws    = (float*)d_ws;                       // NH*S*DH
    float* k_ws    = q_ws + (size_t)NH * S_LEN * DH;
    float* v_ws    = k_ws + (size_t)NH * S_LEN * DH;
    float* st      = v_ws + (size_t)NH * S_LEN * DH;     // NH*NCH*ST_STRIDE
    float* out_pre = st + (size_t)NH * NCH * ST_STRIDE;  // S*DM

    const dim3 gb(DM / 64, S_LEN / 128);   // (16, 16)
    gemm_kernel<1><<<gb, 256, 0, stream>>>(x, Wq, bq, beta, q_ws);
    gemm_kernel<1><<<gb, 256, 0, stream>>>(x, Wk, bk, beta, k_ws);
    gemm_kernel<2><<<gb, 256, 0, stream>>>(x, Wv, bv, beta, v_ws);
    chunk_state_kernel<<<dim3(NCH, NH), 256, 0, stream>>>(k_ws, v_ws, st);
    attn_out_kernel<<<dim3(NCH, NH), 256, 0, stream>>>(q_ws, k_ws, v_ws, st, out_pre);
    gemm_kernel<0><<<gb, 256, 0, stream>>>(out_pre, Wo, bo, beta, out);
}

// Round 2
// 132.947 us; speedup vs baseline: 3.7869x; 3.7869x over previous
//
#include <hip/hip_runtime.h>
#include <hip/hip_bf16.h>
#include <math.h>

#define S_LEN 2048
#define DM    1024
#define NH    16
#define DH    64
#define CHUNK 64
#define NCH   (S_LEN / CHUNK)          // 32
#define ST_STRIDE (DH * DH + DH)       // 4160 floats per (head,chunk) state

typedef __attribute__((ext_vector_type(8))) short bf16x8;   // 8 bf16 in 4 VGPRs
typedef __attribute__((ext_vector_type(4))) float f32x4;

__device__ __forceinline__ float softplus_f(float x) {
    return (x > 20.0f) ? x : log1pf(expf(x));
}

__device__ __forceinline__ ushort bf16r(float f) {   // round-to-nearest-even f32 -> bf16
    union { float f; unsigned int u; } c; c.f = f;
    unsigned int u = c.u;
    u = (u + 0x7FFFu + ((u >> 16) & 1u)) >> 16;
    return (ushort)u;
}

// ---------------- casts ----------------
__global__ __launch_bounds__(256) void cast_x_kernel(const float* __restrict__ src,
                                                     ushort* __restrict__ dst) {
    const int i = (blockIdx.x * 256 + threadIdx.x) * 4;
    const float4 v = *(const float4*)(src + i);
    ushort4 o; o.x = bf16r(v.x); o.y = bf16r(v.y); o.z = bf16r(v.z); o.w = bf16r(v.w);
    *(ushort4*)(dst + i) = o;
}

__global__ __launch_bounds__(256) void cast_w_kernel(const float* __restrict__ Wq,
                                                     const float* __restrict__ Wk,
                                                     const float* __restrict__ Wv,
                                                     const float* __restrict__ Wo,
                                                     ushort* __restrict__ dst) {
    const int y = blockIdx.y;
    const float* s = (y == 0) ? Wq : (y == 1) ? Wk : (y == 2) ? Wv : Wo;
    const int i = (blockIdx.x * 256 + threadIdx.x) * 4;
    const float4 v = *(const float4*)(s + i);
    ushort4 o; o.x = bf16r(v.x); o.y = bf16r(v.y); o.z = bf16r(v.z); o.w = bf16r(v.w);
    *(ushort4*)(dst + (size_t)y * (DM * DM) + i) = o;
}

// ---------------- bf16 MFMA GEMM core (m97 structure) ----------------
// C = A @ B^T.  A: [M][1024] bf16 row-major, B: [N][1024] bf16 row-major (row = output feature).
// Tile BM=128 x BN, BK=32, 4 waves in 2x2, wave sub-tile 64 x BN/2 -> 4 x (BN/32) 16x16 frags.
template<int BN>
__device__ __forceinline__ void gemm_core(const ushort* __restrict__ A,
                                          const ushort* __restrict__ Bw,
                                          int m0, int n0,
                                          ushort* Als, ushort* Bls,
                                          f32x4 acc[4][BN / 32])
{
    constexpr int NF = BN / 32;
    const int t = threadIdx.x;
    const int w = t >> 6, l = t & 63;
    const int wr = w >> 1, wc = w & 1;

#pragma unroll
    for (int mi = 0; mi < 4; ++mi)
#pragma unroll
        for (int ni = 0; ni < NF; ++ni) acc[mi][ni] = (f32x4){0.f, 0.f, 0.f, 0.f};

    const int srow = l >> 2;          // staging: row within 16-row chunk
    const int scol = (l & 3) * 8;     // staging: 8-bf16 column offset
    const int frow = l & 15;          // fragment row
    const int koff = (l >> 4) * 8;    // fragment k offset (contiguous 8)

    for (int kt = 0; kt < DM; kt += 32) {
        // stage A tile (128x32 bf16 = 8 chunks of 1KB); each wave: chunks w, w+4
        __builtin_amdgcn_global_load_lds(
            (const __attribute__((address_space(1))) void*)(A + (size_t)(m0 + w * 16 + srow) * DM + kt + scol),
            (__attribute__((address_space(3))) void*)(Als + w * 512), 16, 0, 0);
        __builtin_amdgcn_global_load_lds(
            (const __attribute__((address_space(1))) void*)(A + (size_t)(m0 + (w + 4) * 16 + srow) * DM + kt + scol),
            (__attribute__((address_space(3))) void*)(Als + (w + 4) * 512), 16, 0, 0);
        // stage B tile (BN x 32)
        __builtin_amdgcn_global_load_lds(
            (const __attribute__((address_space(1))) void*)(Bw + (size_t)(n0 + w * 16 + srow) * DM + kt + scol),
            (__attribute__((address_space(3))) void*)(Bls + w * 512), 16, 0, 0);
        if constexpr (BN == 128) {
            __builtin_amdgcn_global_load_lds(
                (const __attribute__((address_space(1))) void*)(Bw + (size_t)(n0 + (w + 4) * 16 + srow) * DM + kt + scol),
                (__attribute__((address_space(3))) void*)(Bls + (w + 4) * 512), 16, 0, 0);
        }
        __syncthreads();   // drains vmcnt -> staged data visible

        bf16x8 af[4], bfr[NF];
#pragma unroll
        for (int mi = 0; mi < 4; ++mi)
            af[mi] = *(const bf16x8*)&Als[(wr * 64 + mi * 16 + frow) * 32 + koff];
#pragma unroll
        for (int ni = 0; ni < NF; ++ni)
            bfr[ni] = *(const bf16x8*)&Bls[(wc * (BN / 2) + ni * 16 + frow) * 32 + koff];
#pragma unroll
        for (int mi = 0; mi < 4; ++mi)
#pragma unroll
            for (int ni = 0; ni < NF; ++ni)
                acc[mi][ni] = __builtin_amdgcn_mfma_f32_16x16x32_bf16(af[mi], bfr[ni], acc[mi][ni], 0, 0, 0);
        __syncthreads();   // protect LDS before next stage
    }
}

// QKV fused: z=blockIdx.z picks {Wq,Wk,Wv}; out z*S*DM into head layout [(h*S+m)*DH+d], fp32.
// z<2: softplus(v/scale[h]).
__global__ __launch_bounds__(256)
void qkv_gemm_kernel(const ushort* __restrict__ Xb,
                     const ushort* __restrict__ Wqb, const ushort* __restrict__ Wkb,
                     const ushort* __restrict__ Wvb,
                     const float* __restrict__ bq, const float* __restrict__ bk,
                     const float* __restrict__ bv,
                     const float* __restrict__ beta,
                     float* __restrict__ qkv /* q|k|v contiguous */)
{
    __shared__ ushort Als[128 * 32];
    __shared__ ushort Bls[128 * 32];
    const int z = blockIdx.z;
    const ushort* Bw = (z == 0) ? Wqb : (z == 1) ? Wkb : Wvb;
    const float* bias = (z == 0) ? bq : (z == 1) ? bk : bv;
    const int m0 = blockIdx.y * 128;
    const int n0 = blockIdx.x * 128;

    f32x4 acc[4][4];
    gemm_core<128>(Xb, Bw, m0, n0, Als, Bls, acc);

    const int t = threadIdx.x, w = t >> 6, l = t & 63;
    const int wr = w >> 1, wc = w & 1;
    float* outz = qkv + (size_t)z * (NH * S_LEN * DH);

#pragma unroll
    for (int ni = 0; ni < 4; ++ni) {
        const int col = n0 + wc * 64 + ni * 16 + (l & 15);
        const int h = col >> 6, d = col & 63;
        const float bcol = bias[col];
        const float inv = (z < 2) ? (1.0f / (8.0f * expf(beta[h]))) : 1.0f;
#pragma unroll
        for (int mi = 0; mi < 4; ++mi) {
            const int rbase = m0 + wr * 64 + mi * 16 + (l >> 4) * 4;
#pragma unroll
            for (int r = 0; r < 4; ++r) {
                float v = acc[mi][ni][r] + bcol;
                if (z < 2) v = softplus_f(v * inv);
                outz[((size_t)h * S_LEN + rbase + r) * DH + d] = v;
            }
        }
    }
}

// O projection: C = out_pre(bf16) @ Wo^T + bo -> fp32 [2048][1024]. BN=64 -> 256 blocks.
__global__ __launch_bounds__(256)
void o_gemm_kernel(const ushort* __restrict__ Ab, const ushort* __restrict__ Wob,
                   const float* __restrict__ bo, float* __restrict__ out)
{
    __shared__ ushort Als[128 * 32];
    __shared__ ushort Bls[64 * 32];
    const int m0 = blockIdx.y * 128;
    const int n0 = blockIdx.x * 64;

    f32x4 acc[4][2];
    gemm_core<64>(Ab, Wob, m0, n0, Als, Bls, acc);

    const int t = threadIdx.x, w = t >> 6, l = t & 63;
    const int wr = w >> 1, wc = w & 1;
#pragma unroll
    for (int ni = 0; ni < 2; ++ni) {
        const int col = n0 + wc * 32 + ni * 16 + (l & 15);
        const float bcol = bo[col];
#pragma unroll
        for (int mi = 0; mi < 4; ++mi) {
            const int rbase = m0 + wr * 64 + mi * 16 + (l >> 4) * 4;
#pragma unroll
            for (int r = 0; r < 4; ++r)
                out[(size_t)(rbase + r) * DM + col] = acc[mi][ni][r] + bcol;
        }
    }
}

// ---------------- Pass B: per (head, chunk) state ----------------
__global__ __launch_bounds__(256)
void chunk_state_kernel(const float* __restrict__ k_ws, const float* __restrict__ v_ws,
                        float* __restrict__ st)
{
    __shared__ float Ks[64][64];
    __shared__ float Vs[64][64];
    const int c = blockIdx.x, h = blockIdx.y;
    const int t = threadIdx.x;
    const float* Kg = k_ws + ((size_t)h * S_LEN + c * CHUNK) * DH;
    const float* Vg = v_ws + ((size_t)h * S_LEN + c * CHUNK) * DH;
#pragma unroll
    for (int u = 0; u < 4; ++u) {
        int f = u * 256 + t;
        ((float4*)&Ks[0][0])[f] = ((const float4*)Kg)[f];
        ((float4*)&Vs[0][0])[f] = ((const float4*)Vg)[f];
    }
    __syncthreads();

    const int tx = t & 15, ty = t >> 4;
    float acc[4][4];
#pragma unroll
    for (int i = 0; i < 4; ++i)
#pragma unroll
        for (int j = 0; j < 4; ++j) acc[i][j] = 0.0f;

    for (int s = 0; s < 64; ++s) {
        const float4 kd = *(const float4*)&Ks[s][ty * 4];
        const float4 ve = *(const float4*)&Vs[s][tx * 4];
        const float kv[4] = {kd.x, kd.y, kd.z, kd.w};
        const float vv[4] = {ve.x, ve.y, ve.z, ve.w};
#pragma unroll
        for (int i = 0; i < 4; ++i)
#pragma unroll
            for (int j = 0; j < 4; ++j) acc[i][j] += kv[i] * vv[j];
    }
    float* base = st + (size_t)(h * NCH + c) * ST_STRIDE;
#pragma unroll
    for (int i = 0; i < 4; ++i) {
        float4 o; o.x = acc[i][0]; o.y = acc[i][1]; o.z = acc[i][2]; o.w = acc[i][3];
        *(float4*)(base + (ty * 4 + i) * 64 + tx * 4) = o;
    }
    if (t < 64) {
        float s = 0.0f;
        for (int j = 0; j < 64; ++j) s += Ks[j][t];
        base[DH * DH + t] = s;
    }
}

// ---------------- Pass D: per (head, chunk) output (writes bf16 out_pre) ----------------
__global__ __launch_bounds__(256)
void attn_out_kernel(const float* __restrict__ q_ws, const float* __restrict__ k_ws,
                     const float* __restrict__ v_ws, const float* __restrict__ st,
                     ushort* __restrict__ out_pre)
{
    __shared__ float QsT[64][68];
    __shared__ float KsT[64][68];
    __shared__ float Vs[64][64];
    __shared__ float As[64][65];
    __shared__ float KVp[64][64];
    __shared__ float k1p[64];

    const int c = blockIdx.x, h = blockIdx.y;
    const int t = threadIdx.x, tx = t & 15, ty = t >> 4;
    const size_t cbase = ((size_t)h * S_LEN + c * CHUNK) * DH;

#pragma unroll
    for (int u = 0; u < 4; ++u) {
        int f = u * 256 + t;
        int cg = f >> 6, row = f & 63;
        const int col4 = cg * 4;
        const float4 qv = *(const float4*)(q_ws + cbase + (size_t)row * DH + col4);
        QsT[col4 + 0][row] = qv.x;
        QsT[col4 + 1][row] = qv.y;
        QsT[col4 + 2][row] = qv.z;
        QsT[col4 + 3][row] = qv.w;
        const float4 kv = *(const float4*)(k_ws + cbase + (size_t)row * DH + col4);
        KsT[col4 + 0][row] = kv.x;
        KsT[col4 + 1][row] = kv.y;
        KsT[col4 + 2][row] = kv.z;
        KsT[col4 + 3][row] = kv.w;
    }
#pragma unroll
    for (int u = 0; u < 4; ++u) {
        int f = u * 256 + t;
        ((float4*)&Vs[0][0])[f] = ((const float4*)(v_ws + cbase))[f];
    }

    float kvp[4][4];
#pragma unroll
    for (int i = 0; i < 4; ++i)
#pragma unroll
        for (int j = 0; j < 4; ++j) kvp[i][j] = 0.0f;
    float k1r = 0.0f;
    for (int cp = 0; cp < c; ++cp) {
        const float* sb = st + (size_t)(h * NCH + cp) * ST_STRIDE;
#pragma unroll
        for (int i = 0; i < 4; ++i) {
            const float4 m4 = *(const float4*)(sb + (ty * 4 + i) * 64 + tx * 4);
            kvp[i][0] += m4.x; kvp[i][1] += m4.y; kvp[i][2] += m4.z; kvp[i][3] += m4.w;
        }
        if (t < 64) k1r += sb[DH * DH + t];
    }
#pragma unroll
    for (int i = 0; i < 4; ++i) {
        float4 o; o.x = kvp[i][0]; o.y = kvp[i][1]; o.z = kvp[i][2]; o.w = kvp[i][3];
        *(float4*)&KVp[ty * 4 + i][tx * 4] = o;
    }
    if (t < 64) k1p[t] = k1r;
    __syncthreads();

    float a[4][4];
#pragma unroll
    for (int i = 0; i < 4; ++i)
#pragma unroll
        for (int j = 0; j < 4; ++j) a[i][j] = 0.0f;
    for (int d = 0; d < 64; ++d) {
        const float4 qd = *(const float4*)&QsT[d][ty * 4];
        const float4 kd = *(const float4*)&KsT[d][tx * 4];
        const float qv[4] = {qd.x, qd.y, qd.z, qd.w};
        const float kv[4] = {kd.x, kd.y, kd.z, kd.w};
#pragma unroll
        for (int i = 0; i < 4; ++i)
#pragma unroll
            for (int j = 0; j < 4; ++j) a[i][j] += qv[i] * kv[j];
    }
#pragma unroll
    for (int i = 0; i < 4; ++i)
#pragma unroll
        for (int j = 0; j < 4; ++j) {
            const int gi = ty * 4 + i, gj = tx * 4 + j;
            As[gi][gj] = (gj <= gi) ? a[i][j] : 0.0f;
        }

    float num[4][4];
#pragma unroll
    for (int i = 0; i < 4; ++i)
#pragma unroll
        for (int j = 0; j < 4; ++j) num[i][j] = 0.0f;
    for (int d = 0; d < 64; ++d) {
        const float4 qd = *(const float4*)&QsT[d][ty * 4];
        const float4 pe = *(const float4*)&KVp[d][tx * 4];
        const float qv[4] = {qd.x, qd.y, qd.z, qd.w};
        const float pv[4] = {pe.x, pe.y, pe.z, pe.w};
#pragma unroll
        for (int i = 0; i < 4; ++i)
#pragma unroll
            for (int j = 0; j < 4; ++j) num[i][j] += qv[i] * pv[j];
    }
    float den[4] = {0.0f, 0.0f, 0.0f, 0.0f};
    for (int d = 0; d < 64; ++d) {
        const float kp = k1p[d];
#pragma unroll
        for (int i = 0; i < 4; ++i) den[i] += QsT[d][ty * 4 + i] * kp;
    }
    __syncthreads();

    float rs[4] = {0.0f, 0.0f, 0.0f, 0.0f};
    for (int j = 0; j < 64; ++j) {
        const float4 ve = *(const float4*)&Vs[j][tx * 4];
        const float vv[4] = {ve.x, ve.y, ve.z, ve.w};
#pragma unroll
        for (int i = 0; i < 4; ++i) {
            const float aij = As[ty * 4 + i][j];
            rs[i] += aij;
            num[i][0] += aij * vv[0];
            num[i][1] += aij * vv[1];
            num[i][2] += aij * vv[2];
            num[i][3] += aij * vv[3];
        }
    }

#pragma unroll
    for (int i = 0; i < 4; ++i) {
        const float dn = den[i] + rs[i];
        const float r  = 1.0f / dn;
        const int srow = c * CHUNK + ty * 4 + i;
        ushort4 o;
        o.x = bf16r(num[i][0] * r); o.y = bf16r(num[i][1] * r);
        o.z = bf16r(num[i][2] * r); o.w = bf16r(num[i][3] * r);
        *(ushort4*)(out_pre + (size_t)srow * DM + h * DH + tx * 4) = o;
    }
}

extern "C" void kernel_launch(void* const* d_in, const int* in_sizes, int n_in,
                              void* d_out, int out_size, void* d_ws, size_t ws_size,
                              hipStream_t stream)
{
    const float* x    = (const float*)d_in[0];
    const float* Wq   = (const float*)d_in[1];
    const float* bq   = (const float*)d_in[2];
    const float* Wk   = (const float*)d_in[3];
    const float* bk   = (const float*)d_in[4];
    const float* Wv   = (const float*)d_in[5];
    const float* bv   = (const float*)d_in[6];
    const float* Wo   = (const float*)d_in[7];
    const float* bo   = (const float*)d_in[8];
    const float* beta = (const float*)d_in[9];
    float* out = (float*)d_out;

    // workspace layout
    float*  q_ws  = (float*)d_ws;                          // 3 x 2M floats (q|k|v)
    float*  k_ws  = q_ws + (size_t)NH * S_LEN * DH;
    float*  v_ws  = k_ws + (size_t)NH * S_LEN * DH;
    float*  st    = v_ws + (size_t)NH * S_LEN * DH;        // 16*32*4160 floats
    ushort* x_bf  = (ushort*)(st + (size_t)NH * NCH * ST_STRIDE);   // 2M bf16
    ushort* w_bf  = x_bf + (size_t)S_LEN * DM;                      // 4 x 1M bf16
    ushort* op_bf = w_bf + (size_t)4 * DM * DM;                     // 2M bf16

    const ushort* wq_bf = w_bf;
    const ushort* wk_bf = w_bf + (size_t)DM * DM;
    const ushort* wv_bf = w_bf + (size_t)2 * DM * DM;
    const ushort* wo_bf = w_bf + (size_t)3 * DM * DM;

    cast_x_kernel<<<(S_LEN * DM) / 1024, 256, 0, stream>>>(x, x_bf);
    cast_w_kernel<<<dim3((DM * DM) / 1024, 4), 256, 0, stream>>>(Wq, Wk, Wv, Wo, w_bf);

    qkv_gemm_kernel<<<dim3(DM / 128, S_LEN / 128, 3), 256, 0, stream>>>(
        x_bf, wq_bf, wk_bf, wv_bf, bq, bk, bv, beta, q_ws);

    chunk_state_kernel<<<dim3(NCH, NH), 256, 0, stream>>>(k_ws, v_ws, st);
    attn_out_kernel<<<dim3(NCH, NH), 256, 0, stream>>>(q_ws, k_ws, v_ws, st, op_bf);

    o_gemm_kernel<<<dim3(DM / 64, S_LEN / 128), 256, 0, stream>>>(op_bf, wo_bf, bo, out);
}

// Round 3
// 107.432 us; speedup vs baseline: 4.6862x; 1.2375x over previous
//
#include <hip/hip_runtime.h>
#include <hip/hip_bf16.h>
#include <math.h>

#define S_LEN 2048
#define DM    1024
#define NH    16
#define DH    64
#define CHUNK 64
#define NCH   (S_LEN / CHUNK)          // 32
#define ST_STRIDE (DH * DH + DH)       // 4160 floats per (head,chunk) state

typedef __attribute__((ext_vector_type(8))) short bf16x8;   // 8 bf16 in 4 VGPRs
typedef __attribute__((ext_vector_type(4))) float f32x4;

__device__ __forceinline__ float softplus_f(float x) {
    return (x > 20.0f) ? x : log1pf(expf(x));
}

__device__ __forceinline__ ushort bf16r(float f) {   // round-to-nearest-even f32 -> bf16
    union { float f; unsigned int u; } c; c.f = f;
    unsigned int u = c.u;
    u = (u + 0x7FFFu + ((u >> 16) & 1u)) >> 16;
    return (ushort)u;
}

// ---------------- casts ----------------
__global__ __launch_bounds__(256) void cast_x_kernel(const float* __restrict__ src,
                                                     ushort* __restrict__ dst) {
    const int i = (blockIdx.x * 256 + threadIdx.x) * 4;
    const float4 v = *(const float4*)(src + i);
    ushort4 o; o.x = bf16r(v.x); o.y = bf16r(v.y); o.z = bf16r(v.z); o.w = bf16r(v.w);
    *(ushort4*)(dst + i) = o;
}

__global__ __launch_bounds__(256) void cast_w_kernel(const float* __restrict__ Wq,
                                                     const float* __restrict__ Wk,
                                                     const float* __restrict__ Wv,
                                                     const float* __restrict__ Wo,
                                                     ushort* __restrict__ dst) {
    const int y = blockIdx.y;
    const float* s = (y == 0) ? Wq : (y == 1) ? Wk : (y == 2) ? Wv : Wo;
    const int i = (blockIdx.x * 256 + threadIdx.x) * 4;
    const float4 v = *(const float4*)(s + i);
    ushort4 o; o.x = bf16r(v.x); o.y = bf16r(v.y); o.z = bf16r(v.z); o.w = bf16r(v.w);
    *(ushort4*)(dst + (size_t)y * (DM * DM) + i) = o;
}

// ---------------- bf16 MFMA GEMM core (m97 structure) ----------------
// C = A @ B^T.  A: [M][1024] bf16 row-major, B: [N][1024] bf16 row-major (row = output feature).
template<int BN>
__device__ __forceinline__ void gemm_core(const ushort* __restrict__ A,
                                          const ushort* __restrict__ Bw,
                                          int m0, int n0,
                                          ushort* Als, ushort* Bls,
                                          f32x4 acc[4][BN / 32])
{
    constexpr int NF = BN / 32;
    const int t = threadIdx.x;
    const int w = t >> 6, l = t & 63;
    const int wr = w >> 1, wc = w & 1;

#pragma unroll
    for (int mi = 0; mi < 4; ++mi)
#pragma unroll
        for (int ni = 0; ni < NF; ++ni) acc[mi][ni] = (f32x4){0.f, 0.f, 0.f, 0.f};

    const int srow = l >> 2;          // staging: row within 16-row chunk
    const int scol = (l & 3) * 8;     // staging: 8-bf16 column offset
    const int frow = l & 15;          // fragment row
    const int koff = (l >> 4) * 8;    // fragment k offset (contiguous 8)

    for (int kt = 0; kt < DM; kt += 32) {
        __builtin_amdgcn_global_load_lds(
            (const __attribute__((address_space(1))) void*)(A + (size_t)(m0 + w * 16 + srow) * DM + kt + scol),
            (__attribute__((address_space(3))) void*)(Als + w * 512), 16, 0, 0);
        __builtin_amdgcn_global_load_lds(
            (const __attribute__((address_space(1))) void*)(A + (size_t)(m0 + (w + 4) * 16 + srow) * DM + kt + scol),
            (__attribute__((address_space(3))) void*)(Als + (w + 4) * 512), 16, 0, 0);
        __builtin_amdgcn_global_load_lds(
            (const __attribute__((address_space(1))) void*)(Bw + (size_t)(n0 + w * 16 + srow) * DM + kt + scol),
            (__attribute__((address_space(3))) void*)(Bls + w * 512), 16, 0, 0);
        if constexpr (BN == 128) {
            __builtin_amdgcn_global_load_lds(
                (const __attribute__((address_space(1))) void*)(Bw + (size_t)(n0 + (w + 4) * 16 + srow) * DM + kt + scol),
                (__attribute__((address_space(3))) void*)(Bls + (w + 4) * 512), 16, 0, 0);
        }
        __syncthreads();

        bf16x8 af[4], bfr[NF];
#pragma unroll
        for (int mi = 0; mi < 4; ++mi)
            af[mi] = *(const bf16x8*)&Als[(wr * 64 + mi * 16 + frow) * 32 + koff];
#pragma unroll
        for (int ni = 0; ni < NF; ++ni)
            bfr[ni] = *(const bf16x8*)&Bls[(wc * (BN / 2) + ni * 16 + frow) * 32 + koff];
#pragma unroll
        for (int mi = 0; mi < 4; ++mi)
#pragma unroll
            for (int ni = 0; ni < NF; ++ni)
                acc[mi][ni] = __builtin_amdgcn_mfma_f32_16x16x32_bf16(af[mi], bfr[ni], acc[mi][ni], 0, 0, 0);
        __syncthreads();
    }
}

// QKV fused: z picks {Wq,Wk,Wv}; out z*S*DM into head layout [(h*S+m)*DH+d], fp32.
__global__ __launch_bounds__(256)
void qkv_gemm_kernel(const ushort* __restrict__ Xb,
                     const ushort* __restrict__ Wqb, const ushort* __restrict__ Wkb,
                     const ushort* __restrict__ Wvb,
                     const float* __restrict__ bq, const float* __restrict__ bk,
                     const float* __restrict__ bv,
                     const float* __restrict__ beta,
                     float* __restrict__ qkv /* q|k|v contiguous */)
{
    __shared__ ushort Als[128 * 32];
    __shared__ ushort Bls[128 * 32];
    const int z = blockIdx.z;
    const ushort* Bw = (z == 0) ? Wqb : (z == 1) ? Wkb : Wvb;
    const float* bias = (z == 0) ? bq : (z == 1) ? bk : bv;
    const int m0 = blockIdx.y * 128;
    const int n0 = blockIdx.x * 128;

    f32x4 acc[4][4];
    gemm_core<128>(Xb, Bw, m0, n0, Als, Bls, acc);

    const int t = threadIdx.x, w = t >> 6, l = t & 63;
    const int wr = w >> 1, wc = w & 1;
    float* outz = qkv + (size_t)z * (NH * S_LEN * DH);

#pragma unroll
    for (int ni = 0; ni < 4; ++ni) {
        const int col = n0 + wc * 64 + ni * 16 + (l & 15);
        const int h = col >> 6, d = col & 63;
        const float bcol = bias[col];
        const float inv = (z < 2) ? (1.0f / (8.0f * expf(beta[h]))) : 1.0f;
#pragma unroll
        for (int mi = 0; mi < 4; ++mi) {
            const int rbase = m0 + wr * 64 + mi * 16 + (l >> 4) * 4;
#pragma unroll
            for (int r = 0; r < 4; ++r) {
                float v = acc[mi][ni][r] + bcol;
                if (z < 2) v = softplus_f(v * inv);
                outz[((size_t)h * S_LEN + rbase + r) * DH + d] = v;
            }
        }
    }
}

// O projection: C = out_pre(bf16) @ Wo^T + bo -> fp32 [2048][1024].
__global__ __launch_bounds__(256)
void o_gemm_kernel(const ushort* __restrict__ Ab, const ushort* __restrict__ Wob,
                   const float* __restrict__ bo, float* __restrict__ out)
{
    __shared__ ushort Als[128 * 32];
    __shared__ ushort Bls[64 * 32];
    const int m0 = blockIdx.y * 128;
    const int n0 = blockIdx.x * 64;

    f32x4 acc[4][2];
    gemm_core<64>(Ab, Wob, m0, n0, Als, Bls, acc);

    const int t = threadIdx.x, w = t >> 6, l = t & 63;
    const int wr = w >> 1, wc = w & 1;
#pragma unroll
    for (int ni = 0; ni < 2; ++ni) {
        const int col = n0 + wc * 32 + ni * 16 + (l & 15);
        const float bcol = bo[col];
#pragma unroll
        for (int mi = 0; mi < 4; ++mi) {
            const int rbase = m0 + wr * 64 + mi * 16 + (l >> 4) * 4;
#pragma unroll
            for (int r = 0; r < 4; ++r)
                out[(size_t)(rbase + r) * DM + col] = acc[mi][ni][r] + bcol;
        }
    }
}

// ---------------- Pass B: per (head, chunk) state ----------------
__global__ __launch_bounds__(256)
void chunk_state_kernel(const float* __restrict__ k_ws, const float* __restrict__ v_ws,
                        float* __restrict__ st)
{
    __shared__ float Ks[64][64];
    __shared__ float Vs[64][64];
    const int c = blockIdx.x, h = blockIdx.y;
    const int t = threadIdx.x;
    const float* Kg = k_ws + ((size_t)h * S_LEN + c * CHUNK) * DH;
    const float* Vg = v_ws + ((size_t)h * S_LEN + c * CHUNK) * DH;
#pragma unroll
    for (int u = 0; u < 4; ++u) {
        int f = u * 256 + t;
        ((float4*)&Ks[0][0])[f] = ((const float4*)Kg)[f];
        ((float4*)&Vs[0][0])[f] = ((const float4*)Vg)[f];
    }
    __syncthreads();

    const int tx = t & 15, ty = t >> 4;
    float acc[4][4];
#pragma unroll
    for (int i = 0; i < 4; ++i)
#pragma unroll
        for (int j = 0; j < 4; ++j) acc[i][j] = 0.0f;

    for (int s = 0; s < 64; ++s) {
        const float4 kd = *(const float4*)&Ks[s][ty * 4];
        const float4 ve = *(const float4*)&Vs[s][tx * 4];
        const float kv[4] = {kd.x, kd.y, kd.z, kd.w};
        const float vv[4] = {ve.x, ve.y, ve.z, ve.w};
#pragma unroll
        for (int i = 0; i < 4; ++i)
#pragma unroll
            for (int j = 0; j < 4; ++j) acc[i][j] += kv[i] * vv[j];
    }
    float* base = st + (size_t)(h * NCH + c) * ST_STRIDE;
#pragma unroll
    for (int i = 0; i < 4; ++i) {
        float4 o; o.x = acc[i][0]; o.y = acc[i][1]; o.z = acc[i][2]; o.w = acc[i][3];
        *(float4*)(base + (ty * 4 + i) * 64 + tx * 4) = o;
    }
    if (t < 64) {
        float s = 0.0f;
        for (int j = 0; j < 64; ++j) s += Ks[j][t];
        base[DH * DH + t] = s;
    }
}

// ---------------- Pass C: in-place exclusive prefix scan over chunks ----------------
// st[(h*NCH+c)*ST_STRIDE + e]  ->  sum over c' < c.  Each thread owns one (h,e).
__global__ __launch_bounds__(64)
void scan_kernel(float* __restrict__ st)
{
    const int h = blockIdx.y;
    const int e = blockIdx.x * 64 + threadIdx.x;   // e in [0, ST_STRIDE)
    float* p = st + (size_t)h * NCH * ST_STRIDE + e;
    float acc = 0.0f;
    for (int c = 0; c < NCH; ++c) {
        const float v = p[(size_t)c * ST_STRIDE];
        p[(size_t)c * ST_STRIDE] = acc;            // exclusive prefix (load-before-store, same thread)
        acc += v;
    }
}

// ---------------- Pass D: per (head, chunk) output ----------------
// num = maskedQK^T @ V + Q @ KVpfx ;  den = rowsum(maskedQK^T) + Q . k1pfx ;  out = num/den (bf16)
__global__ __launch_bounds__(256)
void attn_out_kernel(const float* __restrict__ q_ws, const float* __restrict__ k_ws,
                     const float* __restrict__ v_ws, const float* __restrict__ pfx,
                     ushort* __restrict__ out_pre)
{
    __shared__ float QsT[64][68];   // [d][i]
    __shared__ float KsT[64][68];   // [d][j]
    __shared__ float Vs[64][64];    // [j][e]
    __shared__ float As[64][65];    // [i][j]

    const int c = blockIdx.x, h = blockIdx.y;
    const int t = threadIdx.x, tx = t & 15, ty = t >> 4;
    const size_t cbase = ((size_t)h * S_LEN + c * CHUNK) * DH;
    const float* __restrict__ pb = pfx + (size_t)(h * NCH + c) * ST_STRIDE;

#pragma unroll
    for (int u = 0; u < 4; ++u) {
        int f = u * 256 + t;
        int cg = f >> 6, row = f & 63;
        const int col4 = cg * 4;
        const float4 qv = *(const float4*)(q_ws + cbase + (size_t)row * DH + col4);
        QsT[col4 + 0][row] = qv.x;
        QsT[col4 + 1][row] = qv.y;
        QsT[col4 + 2][row] = qv.z;
        QsT[col4 + 3][row] = qv.w;
        const float4 kv = *(const float4*)(k_ws + cbase + (size_t)row * DH + col4);
        KsT[col4 + 0][row] = kv.x;
        KsT[col4 + 1][row] = kv.y;
        KsT[col4 + 2][row] = kv.z;
        KsT[col4 + 3][row] = kv.w;
    }
#pragma unroll
    for (int u = 0; u < 4; ++u) {
        int f = u * 256 + t;
        ((float4*)&Vs[0][0])[f] = ((const float4*)(v_ws + cbase))[f];
    }
    __syncthreads();

    // A = Q K^T  (tile i = ty*4.., j = tx*4..)
    float a[4][4];
#pragma unroll
    for (int i = 0; i < 4; ++i)
#pragma unroll
        for (int j = 0; j < 4; ++j) a[i][j] = 0.0f;
    for (int d = 0; d < 64; ++d) {
        const float4 qd = *(const float4*)&QsT[d][ty * 4];
        const float4 kd = *(const float4*)&KsT[d][tx * 4];
        const float qv[4] = {qd.x, qd.y, qd.z, qd.w};
        const float kv[4] = {kd.x, kd.y, kd.z, kd.w};
#pragma unroll
        for (int i = 0; i < 4; ++i)
#pragma unroll
            for (int j = 0; j < 4; ++j) a[i][j] += qv[i] * kv[j];
    }
#pragma unroll
    for (int i = 0; i < 4; ++i)
#pragma unroll
        for (int j = 0; j < 4; ++j) {
            const int gi = ty * 4 + i, gj = tx * 4 + j;
            As[gi][gj] = (gj <= gi) ? a[i][j] : 0.0f;
        }

    // inter-chunk from the precomputed exclusive-prefix state (L2/L1-resident):
    //   num += Q @ KVpfx ; den = Q . k1pfx     (fused loop, reads QsT + global pfx)
    float num[4][4];
#pragma unroll
    for (int i = 0; i < 4; ++i)
#pragma unroll
        for (int j = 0; j < 4; ++j) num[i][j] = 0.0f;
    float den[4] = {0.0f, 0.0f, 0.0f, 0.0f};
#pragma unroll 4
    for (int d = 0; d < 64; ++d) {
        const float4 qd = *(const float4*)&QsT[d][ty * 4];
        const float4 pe = *(const float4*)(pb + d * 64 + tx * 4);
        const float kp = pb[DH * DH + d];            // wave-uniform -> scalar path
        const float qv[4] = {qd.x, qd.y, qd.z, qd.w};
        const float pv[4] = {pe.x, pe.y, pe.z, pe.w};
#pragma unroll
        for (int i = 0; i < 4; ++i) {
#pragma unroll
            for (int j = 0; j < 4; ++j) num[i][j] += qv[i] * pv[j];
            den[i] += qv[i] * kp;
        }
    }
    __syncthreads();   // As fully written

    // intra-chunk: num += A V ; rowsum(A)
    float rs[4] = {0.0f, 0.0f, 0.0f, 0.0f};
    for (int j = 0; j < 64; ++j) {
        const float4 ve = *(const float4*)&Vs[j][tx * 4];
        const float vv[4] = {ve.x, ve.y, ve.z, ve.w};
#pragma unroll
        for (int i = 0; i < 4; ++i) {
            const float aij = As[ty * 4 + i][j];
            rs[i] += aij;
            num[i][0] += aij * vv[0];
            num[i][1] += aij * vv[1];
            num[i][2] += aij * vv[2];
            num[i][3] += aij * vv[3];
        }
    }

#pragma unroll
    for (int i = 0; i < 4; ++i) {
        const float dn = den[i] + rs[i];
        const float r  = 1.0f / dn;
        const int srow = c * CHUNK + ty * 4 + i;
        ushort4 o;
        o.x = bf16r(num[i][0] * r); o.y = bf16r(num[i][1] * r);
        o.z = bf16r(num[i][2] * r); o.w = bf16r(num[i][3] * r);
        *(ushort4*)(out_pre + (size_t)srow * DM + h * DH + tx * 4) = o;
    }
}

extern "C" void kernel_launch(void* const* d_in, const int* in_sizes, int n_in,
                              void* d_out, int out_size, void* d_ws, size_t ws_size,
                              hipStream_t stream)
{
    const float* x    = (const float*)d_in[0];
    const float* Wq   = (const float*)d_in[1];
    const float* bq   = (const float*)d_in[2];
    const float* Wk   = (const float*)d_in[3];
    const float* bk   = (const float*)d_in[4];
    const float* Wv   = (const float*)d_in[5];
    const float* bv   = (const float*)d_in[6];
    const float* Wo   = (const float*)d_in[7];
    const float* bo   = (const float*)d_in[8];
    const float* beta = (const float*)d_in[9];
    float* out = (float*)d_out;

    float*  q_ws  = (float*)d_ws;                          // 3 x 2M floats (q|k|v)
    float*  k_ws  = q_ws + (size_t)NH * S_LEN * DH;
    float*  v_ws  = k_ws + (size_t)NH * S_LEN * DH;
    float*  st    = v_ws + (size_t)NH * S_LEN * DH;        // 16*32*4160 floats
    ushort* x_bf  = (ushort*)(st + (size_t)NH * NCH * ST_STRIDE);   // 2M bf16
    ushort* w_bf  = x_bf + (size_t)S_LEN * DM;                      // 4 x 1M bf16
    ushort* op_bf = w_bf + (size_t)4 * DM * DM;                     // 2M bf16

    const ushort* wq_bf = w_bf;
    const ushort* wk_bf = w_bf + (size_t)DM * DM;
    const ushort* wv_bf = w_bf + (size_t)2 * DM * DM;
    const ushort* wo_bf = w_bf + (size_t)3 * DM * DM;

    cast_x_kernel<<<(S_LEN * DM) / 1024, 256, 0, stream>>>(x, x_bf);
    cast_w_kernel<<<dim3((DM * DM) / 1024, 4), 256, 0, stream>>>(Wq, Wk, Wv, Wo, w_bf);

    qkv_gemm_kernel<<<dim3(DM / 128, S_LEN / 128, 3), 256, 0, stream>>>(
        x_bf, wq_bf, wk_bf, wv_bf, bq, bk, bv, beta, q_ws);

    chunk_state_kernel<<<dim3(NCH, NH), 256, 0, stream>>>(k_ws, v_ws, st);
    scan_kernel<<<dim3(ST_STRIDE / 64, NH), 64, 0, stream>>>(st);   // st -> exclusive prefixes
    attn_out_kernel<<<dim3(NCH, NH), 256, 0, stream>>>(q_ws, k_ws, v_ws, st, op_bf);

    o_gemm_kernel<<<dim3(DM / 64, S_LEN / 128), 256, 0, stream>>>(op_bf, wo_bf, bo, out);
}